// Round 7
// baseline (763.514 us; speedup 1.0000x reference)
//
#include <hip/hip_runtime.h>
#include <math.h>

// eval-mode BatchNorm3d scale: np.float32(1/sqrt(1+1e-5))
#define BN_S 0.9999950000374997f

typedef _Float16 half8 __attribute__((ext_vector_type(8)));
typedef float f32x4 __attribute__((ext_vector_type(4)));

__device__ __forceinline__ float silu_f(float x) {
    return __fdividef(x, 1.0f + __expf(-x));
}

// global -> LDS async DMA, 16B per lane (lane-linear LDS destination)
__device__ __forceinline__ void gld16(const void* g, void* l) {
    __builtin_amdgcn_global_load_lds(
        (const __attribute__((address_space(1))) void*)g,
        (__attribute__((address_space(3))) void*)l, 16, 0, 0);
}

// ---------------------------------------------------------------------------
// Prep: W_mu = mw2 @ uw1, b_mu = mb2 @ uw1 + ub1, and W_em^T = (ew2 @ mw1[64:])^T
// split to fp16 hi/lo in the edge kernel's DMA/frag layout (XOR-swizzled).
// ---------------------------------------------------------------------------
__global__ __launch_bounds__(64) void prep_w_k(
    const float* __restrict__ ew2, const float* __restrict__ mw1,
    const float* __restrict__ mw2, const float* __restrict__ uw1,
    const float* __restrict__ mb2, const float* __restrict__ ub1,
    float* __restrict__ W_mu, float* __restrict__ b_mu,
    _Float16* __restrict__ wemt_h, _Float16* __restrict__ wemt_l)
{
    const int k = blockIdx.x, c = threadIdx.x;
    float s = 0.f;
    for (int m = 0; m < 64; m++) s = fmaf(ew2[k*64 + m], mw1[(64 + m)*64 + c], s);
    {
        const int q = k >> 5, kg = (k >> 3) & 3, jj = k & 7;
        const int sl = q*256 + c*4 + kg;
        const int p = sl ^ ((sl >> 3) & 7);
        const _Float16 h = (_Float16)s;
        const _Float16 l = (_Float16)(s - (float)h);
        wemt_h[p*8 + jj] = h;
        wemt_l[p*8 + jj] = l;
    }
    float s2 = 0.f;
    for (int m = 0; m < 64; m++) s2 = fmaf(mw2[k*64 + m], uw1[m*64 + c], s2);
    W_mu[k*64 + c] = s2;
    if (k == 0) {
        float s3 = ub1[c];
        for (int m = 0; m < 64; m++) s3 = fmaf(mb2[m], uw1[m*64 + c], s3);
        b_mu[c] = s3;
    }
}

// ---------------------------------------------------------------------------
__global__ __launch_bounds__(64) void prep_nodes_k(
    const float* __restrict__ node_embedding, const float* __restrict__ node_pos,
    const float* __restrict__ grid_pos, const float* __restrict__ ew1,
    const float* __restrict__ eb1, const float* __restrict__ mw1,
    const float* __restrict__ mb1, const float* __restrict__ eb2,
    float* __restrict__ a_node, float* __restrict__ g_vox, float* __restrict__ n_node)
{
    const int v = blockIdx.x, c = threadIdx.x;
    const float p0 = node_pos[v*3], p1 = node_pos[v*3 + 1], p2 = node_pos[v*3 + 2];
    a_node[v*64 + c] = fmaf(p0, ew1[c], fmaf(p1, ew1[64 + c], fmaf(p2, ew1[128 + c], eb1[c])));
    const float q0 = grid_pos[v*3], q1 = grid_pos[v*3 + 1], q2 = grid_pos[v*3 + 2];
    g_vox[v*64 + c] = fmaf(q0, ew1[192 + c], fmaf(q1, ew1[256 + c], q2 * ew1[320 + c]));
    float s = mb1[c];
    for (int k = 0; k < 64; k++) s = fmaf(node_embedding[v*64 + k], mw1[k*64 + c], s);
    for (int k = 0; k < 64; k++) s = fmaf(eb2[k], mw1[(64 + k)*64 + c], s);
    n_node[v*64 + c] = s;
}

// ---------------------------------------------------------------------------
// Weight transpose + fp16 hi/lo split into conv layout (unchanged):
// per (tap, coG, ch): 2048 f16 = [co64][ci32] with 16B-slot XOR swizzle.
// ---------------------------------------------------------------------------
template<int K3, int NCOG, int NCH>
__global__ __launch_bounds__(256) void wsplit_k(
    const float* __restrict__ w, _Float16* __restrict__ dh, _Float16* __restrict__ dl,
    int CI)
{
    __shared__ float s[32*K3];
    const int co = blockIdx.x, cig = blockIdx.y, t = threadIdx.x;
    const float* src = w + ((size_t)co*CI + cig*32)*K3;
    for (int m = t; m < 32*K3; m += 256) s[m] = src[m];
    __syncthreads();
    const int coG = co >> 6, col = co & 63;
    for (int m = t; m < 32*K3; m += 256) {
        const int tap = m >> 5, cil = m & 31;
        const float x = s[cil*K3 + tap];
        const _Float16 h = (_Float16)x;
        const _Float16 l = (_Float16)(x - (float)h);
        const int b = cil >> 3, jj = cil & 7;
        const int sl = col*4 + b;
        const int p = sl ^ ((sl >> 3) & 7);
        const size_t base = ((size_t)(tap*NCOG + coG)*NCH + cig) * 2048;
        dh[base + p*8 + jj] = h;
        dl[base + p*8 + jj] = l;
    }
}

// ---------------------------------------------------------------------------
// Edge kernel, MFMA version (unchanged — passed with absmax 0.0).
// ---------------------------------------------------------------------------
__global__ __launch_bounds__(256) void edge_kernel(
    const int* __restrict__ edge_i,
    const float* __restrict__ a_node, const float* __restrict__ g_vox,
    const float* __restrict__ n_node,
    const _Float16* __restrict__ wemt_h, const _Float16* __restrict__ wemt_l,
    const float* __restrict__ W_mu, const float* __restrict__ b_mu,
    const float* __restrict__ uw2, const float* __restrict__ ub2,
    _Float16* __restrict__ x0h, _Float16* __restrict__ x0l)
{
    __shared__ __align__(16) _Float16 sAh[4096], sAl[4096];
    __shared__ __align__(16) _Float16 sBh[4096], sBl[4096];
    __shared__ float sV1[64], sV2[64];

    const int j = blockIdx.x, t = threadIdx.x;
    const int lane = t & 63, wv = t >> 6, ln15 = lane & 15, kg = lane >> 4;
    const int ebase = j << 8;

    gld16(wemt_h + t*8, &sAh[t*8]);
    gld16(wemt_h + 2048 + t*8, &sAh[2048 + t*8]);
    gld16(wemt_l + t*8, &sAl[t*8]);
    gld16(wemt_l + 2048 + t*8, &sAl[2048 + t*8]);

    const int r = t >> 2, sub = t & 3;
    float gv[16];
    #pragma unroll
    for (int m = 0; m < 16; m++) gv[m] = g_vox[j*64 + sub*16 + m];

    asm volatile("s_waitcnt vmcnt(0)" ::: "memory");
    __syncthreads();

    float psum[4] = {0.f, 0.f, 0.f, 0.f};

    for (int T = 0; T < 4; T++) {
        {
            const int i = edge_i[ebase + T*64 + r];
            float s1[16];
            #pragma unroll
            for (int m = 0; m < 16; m++)
                s1[m] = silu_f(a_node[i*64 + sub*16 + m] + gv[m]);
            half8 h0, l0, h1, l1;
            #pragma unroll
            for (int m = 0; m < 8; m++) {
                h0[m] = (_Float16)s1[m];
                l0[m] = (_Float16)(s1[m] - (float)h0[m]);
                h1[m] = (_Float16)s1[8 + m];
                l1[m] = (_Float16)(s1[8 + m] - (float)h1[m]);
            }
            const int q = sub >> 1, kg0 = (sub & 1) * 2;
            const int slot0 = (q*4 + kg0)*64 + r;
            *(half8*)&sBh[slot0*8] = h0; *(half8*)&sBl[slot0*8] = l0;
            *(half8*)&sBh[(slot0 + 64)*8] = h1; *(half8*)&sBl[(slot0 + 64)*8] = l1;
        }
        __syncthreads();
        #pragma unroll
        for (int eF = 0; eF < 4; eF++) {
            const int e = eF*16 + ln15;
            const int ie = edge_i[ebase + T*64 + e];
            f32x4 acc;
            {
                const float4 nv = *(const float4*)&n_node[(size_t)ie*64 + wv*16 + kg*4];
                acc[0] = nv.x; acc[1] = nv.y; acc[2] = nv.z; acc[3] = nv.w;
            }
            #pragma unroll
            for (int q = 0; q < 2; q++) {
                const int sa = q*256 + (wv*16 + ln15)*4 + kg;
                const int pa = sa ^ ((sa >> 3) & 7);
                const half8 Ah = *(const half8*)&sAh[pa*8];
                const half8 Al = *(const half8*)&sAl[pa*8];
                const int sb = ((q*4 + kg)*64 + e)*8;
                const half8 Bh = *(const half8*)&sBh[sb];
                const half8 Bl = *(const half8*)&sBl[sb];
                acc = __builtin_amdgcn_mfma_f32_16x16x32_f16(Ah, Bh, acc, 0, 0, 0);
                acc = __builtin_amdgcn_mfma_f32_16x16x32_f16(Ah, Bl, acc, 0, 0, 0);
                acc = __builtin_amdgcn_mfma_f32_16x16x32_f16(Al, Bh, acc, 0, 0, 0);
            }
            #pragma unroll
            for (int rg = 0; rg < 4; rg++) psum[rg] += silu_f(acc[rg]);
        }
        __syncthreads();
    }

    #pragma unroll
    for (int rg = 0; rg < 4; rg++) {
        float v = psum[rg];
        v += __shfl_xor(v, 1, 64); v += __shfl_xor(v, 2, 64);
        v += __shfl_xor(v, 4, 64); v += __shfl_xor(v, 8, 64);
        psum[rg] = v;
    }
    if (ln15 == 0) {
        #pragma unroll
        for (int rg = 0; rg < 4; rg++)
            sV1[wv*16 + kg*4 + rg] = psum[rg] * (1.0f / 256.0f);
    }
    __syncthreads();
    if (t < 64) {
        float h = b_mu[t];
        for (int k = 0; k < 64; k++) h = fmaf(sV1[k], W_mu[k*64 + t], h);
        sV2[t] = silu_f(h);
    }
    __syncthreads();
    if (t < 64) {
        float g = ub2[t];
        for (int k = 0; k < 64; k++) g = fmaf(sV2[k], uw2[k*64 + t], g);
        const float val = g * BN_S;
        const _Float16 hh = (_Float16)val;
        const _Float16 ll = (_Float16)(val - (float)hh);
        const int c = t, zz = j >> 8, v = j & 255;
        const size_t a16 = ((size_t)((c >> 5)*16 + zz)*1024 + ((c >> 3) & 3)*256 + v)*8 + (c & 7);
        x0h[a16] = hh; x0l[a16] = ll;
    }
}

// ---------------------------------------------------------------------------
// Conv3D via MFMA shift-GEMM v6: full 2-stage register pipeline.
// Per tap t: issue A(t+1) global loads + B(t+1) ds_reads into ping/pong reg
// sets, THEN run tap t's 48-MFMA burst (covers both latencies). Tap loop
// manually 2x-unrolled so all register indices are compile-time. One
// vmcnt(0)+barrier per 32-ci chunk only.
// grid(d0=16, coG, z = cis*KK + kd); slab index = blockIdx.z; S = CIS*KK.
// ---------------------------------------------------------------------------
template<int KK, int CI, int NCOG, int CIS>
__global__ __launch_bounds__(256, 2) void conv_mfma_k(
    const _Float16* __restrict__ xh, const _Float16* __restrict__ xl,
    const _Float16* __restrict__ wh, const _Float16* __restrict__ wl,
    float* __restrict__ slab)
{
    constexpr int P = KK/2, K2 = KK*KK, NCH = CI/32, NCHS = NCH/CIS, CO = NCOG*64;
    const int d0 = blockIdx.x, coG = blockIdx.y;
    const int cis = blockIdx.z / KK, kd = blockIdx.z % KK;
    const int t = threadIdx.x;
    const int lane = t & 63, wv = t >> 6;
    const int ln15 = lane & 15, kg = lane >> 4;

    float* sout = slab + ((size_t)blockIdx.z*CO + coG*64)*4096 + d0*256;
    const int z = d0 + kd - P;
    if ((unsigned)z >= 16u) {   // OOB depth plane -> zero partial
        for (int m = t; m < 64*256; m += 256)
            sout[(size_t)(m >> 8)*4096 + (m & 255)] = 0.f;
        return;
    }

    __shared__ __align__(16) _Float16 sXh[2][8192];   // 32 KB
    __shared__ __align__(16) _Float16 sXl[2][8192];   // 32 KB
    __shared__ __align__(16) _Float16 zb[8];
    if (t < 8) zb[t] = (_Float16)0.f;

    // per-lane A fragment offsets (swizzled), constant across taps
    int aoff[4];
    #pragma unroll
    for (int cf = 0; cf < 4; cf++) {
        const int s = (cf*16 + ln15)*4 + kg;
        aoff[cf] = (s ^ ((s >> 3) & 7)) * 8;
    }

    auto stage_X = [&](int xb, int ch) {
        const size_t b16 = ((size_t)ch*16 + z) * 8192;
        #pragma unroll
        for (int q = 0; q < 4; q++) {
            gld16(xh + b16 + (q*256 + t)*8, &sXh[xb][(q*256 + t)*8]);
            gld16(xl + b16 + (q*256 + t)*8, &sXl[xb][(q*256 + t)*8]);
        }
    };
    auto loadA = [&](int ch, int t2, half8* Ah, half8* Al) {
        const size_t b = ((size_t)((kd*K2 + t2)*NCOG + coG)*NCH + ch) * 2048;
        #pragma unroll
        for (int cf = 0; cf < 4; cf++) {
            Ah[cf] = *(const half8*)&wh[b + aoff[cf]];
            Al[cf] = *(const half8*)&wl[b + aoff[cf]];
        }
    };
    auto loadB = [&](int t2, int xb, half8* Bh, half8* Bl) {
        const int kh = t2 / KK, kw = t2 - kh*KK;
        const int w_in = ln15 + kw - P;
        const bool okw = (unsigned)w_in < 16u;
        #pragma unroll
        for (int f = 0; f < 4; f++) {
            const int h_in = wv*4 + f + kh - P;      // wave-uniform
            if ((unsigned)h_in < 16u) {
                const int slot = kg*256 + h_in*16 + (okw ? w_in : 0);
                const _Float16* ph = okw ? &sXh[xb][slot*8] : zb;
                const _Float16* pl = okw ? &sXl[xb][slot*8] : zb;
                Bh[f] = *(const half8*)ph;
                Bl[f] = *(const half8*)pl;
            }
        }
    };

    f32x4 acc[4][4];
    #pragma unroll
    for (int a = 0; a < 4; a++)
        #pragma unroll
        for (int b = 0; b < 4; b++)
            #pragma unroll
            for (int r2 = 0; r2 < 4; r2++) acc[a][b][r2] = 0.f;

    auto burst = [&](int t2, const half8* Bh, const half8* Bl,
                     const half8* Ah, const half8* Al) {
        const int kh = t2 / KK;
        __builtin_amdgcn_s_setprio(1);
        #pragma unroll
        for (int f = 0; f < 4; f++) {
            const int h_in = wv*4 + f + kh - P;
            if ((unsigned)h_in < 16u) {
                #pragma unroll
                for (int cf = 0; cf < 4; cf++) {
                    acc[cf][f] = __builtin_amdgcn_mfma_f32_16x16x32_f16(Ah[cf], Bh[f], acc[cf][f], 0, 0, 0);
                    acc[cf][f] = __builtin_amdgcn_mfma_f32_16x16x32_f16(Ah[cf], Bl[f], acc[cf][f], 0, 0, 0);
                    acc[cf][f] = __builtin_amdgcn_mfma_f32_16x16x32_f16(Al[cf], Bh[f], acc[cf][f], 0, 0, 0);
                }
            }
        }
        __builtin_amdgcn_s_setprio(0);
    };

    half8 A0h[4], A0l[4], A1h[4], A1l[4];
    half8 B0h[4], B0l[4], B1h[4], B1l[4];

    const int ch0 = cis * NCHS;
    stage_X(0, ch0);
    loadA(ch0, 0, A0h, A0l);
    asm volatile("s_waitcnt vmcnt(0)" ::: "memory");
    __syncthreads();

    for (int cc = 0; cc < NCHS; cc++) {
        const int ch = ch0 + cc, xb = cc & 1;
        if (cc + 1 < NCHS) stage_X(xb ^ 1, ch + 1);   // DMA flies across the chunk
        loadB(0, xb, B0h, B0l);

        int t2 = 0;
        for (; t2 + 2 <= K2; t2 += 2) {
            // tap t2 (set0); prefetch t2+1 into set1
            loadA(ch, t2 + 1, A1h, A1l);
            loadB(t2 + 1, xb, B1h, B1l);
            burst(t2, B0h, B0l, A0h, A0l);
            // tap t2+1 (set1); prefetch t2+2 into set0
            if (t2 + 2 < K2) {
                loadA(ch, t2 + 2, A0h, A0l);
                loadB(t2 + 2, xb, B0h, B0l);
            } else if (cc + 1 < NCHS) {
                loadA(ch + 1, 0, A0h, A0l);
            }
            burst(t2 + 1, B1h, B1l, A1h, A1l);
        }
        if (t2 < K2) {   // K2 odd: tail tap in set0
            if (cc + 1 < NCHS) loadA(ch + 1, 0, A1h, A1l);
            burst(t2, B0h, B0l, A0h, A0l);
            if (cc + 1 < NCHS) {
                #pragma unroll
                for (int cf = 0; cf < 4; cf++) { A0h[cf] = A1h[cf]; A0l[cf] = A1l[cf]; }
            }
        }
        asm volatile("s_waitcnt vmcnt(0)" ::: "memory");
        __syncthreads();   // staging of next buffer landed; xb free for overwrite
    }

    // C frag: col=lane&15 (vox), row=(lane>>4)*4+reg (co)
    #pragma unroll
    for (int cf = 0; cf < 4; cf++)
        #pragma unroll
        for (int f = 0; f < 4; f++)
            #pragma unroll
            for (int r2 = 0; r2 < 4; r2++)
                sout[(size_t)(cf*16 + kg*4 + r2)*4096 + wv*64 + f*16 + ln15] = acc[cf][f][r2];
}

// ---------------------------------------------------------------------------
// Reduce S kd/cis-slabs + BN (+residual) (+relu); emit fp32 / fp16-split /
// poolmax partials. grid(16 z, CO/8).
// ---------------------------------------------------------------------------
template<int S, int RMODE, int OUT>
__global__ __launch_bounds__(256) void reduce_k(
    const float* __restrict__ pbuf, const float* __restrict__ addsrc,
    float* __restrict__ outf, _Float16* __restrict__ oh, _Float16* __restrict__ ol,
    int CO)
{
    const int z = blockIdx.x, c8 = blockIdx.y, v = threadIdx.x;
    float val[8];
    #pragma unroll
    for (int jj = 0; jj < 8; jj++) {
        const int c = c8*8 + jj;
        float a = 0.f;
        #pragma unroll
        for (int s = 0; s < S; s++)
            a += pbuf[((size_t)s*CO + c)*4096 + z*256 + v];
        a *= BN_S;
        if (RMODE == 3) a += addsrc[(size_t)c*4096 + z*256 + v];
        if (RMODE != 2) a = fmaxf(a, 0.f);
        val[jj] = a;
    }
    if (OUT == 0) {
        #pragma unroll
        for (int jj = 0; jj < 8; jj++)
            outf[(size_t)(c8*8 + jj)*4096 + z*256 + v] = val[jj];
    } else if (OUT == 1) {
        half8 hv, lv;
        #pragma unroll
        for (int jj = 0; jj < 8; jj++) {
            hv[jj] = (_Float16)val[jj];
            lv[jj] = (_Float16)(val[jj] - (float)hv[jj]);
        }
        const size_t a16 = ((size_t)((c8 >> 2)*16 + z)*1024 + (c8 & 3)*256 + v)*8;
        *(half8*)&oh[a16] = hv;
        *(half8*)&ol[a16] = lv;
    } else {
        __shared__ float sm[4][8];
        #pragma unroll
        for (int jj = 0; jj < 8; jj++) {
            float m = val[jj];
            m = fmaxf(m, __shfl_xor(m, 1, 64));  m = fmaxf(m, __shfl_xor(m, 2, 64));
            m = fmaxf(m, __shfl_xor(m, 4, 64));  m = fmaxf(m, __shfl_xor(m, 8, 64));
            m = fmaxf(m, __shfl_xor(m, 16, 64)); m = fmaxf(m, __shfl_xor(m, 32, 64));
            if ((v & 63) == 0) sm[v >> 6][jj] = m;
        }
        __syncthreads();
        if (v < 8) {
            const float m = fmaxf(fmaxf(sm[0][v], sm[1][v]), fmaxf(sm[2][v], sm[3][v]));
            outf[z*CO + c8*8 + v] = m;
        }
    }
}

// ---------------------------------------------------------------------------
__global__ __launch_bounds__(256) void fc_k(
    const float* __restrict__ pp, const float* __restrict__ fcw,
    const float* __restrict__ fcb, float* __restrict__ out)
{
    __shared__ float sp[256];
    const int t = threadIdx.x;
    float m = pp[t];
    for (int zz = 1; zz < 16; zz++) m = fmaxf(m, pp[zz*256 + t]);
    sp[t] = m;
    __syncthreads();
    if (t < 20) {
        float s = fcb[t];
        for (int c = 0; c < 256; c++) s = fmaf(sp[c], fcw[c*20 + t], s);
        out[t] = s;
    }
}

// ---------------------------------------------------------------------------
extern "C" void kernel_launch(void* const* d_in, const int* in_sizes, int n_in,
                              void* d_out, int out_size, void* d_ws, size_t ws_size,
                              hipStream_t stream)
{
    const float* node_embedding = (const float*)d_in[0];
    const float* node_pos       = (const float*)d_in[1];
    const float* grid_pos       = (const float*)d_in[2];
    const int*   edge_index     = (const int*)d_in[3];
    const float* ew1 = (const float*)d_in[4];
    const float* eb1 = (const float*)d_in[5];
    const float* ew2 = (const float*)d_in[6];
    const float* eb2 = (const float*)d_in[7];
    const float* mw1 = (const float*)d_in[8];
    const float* mb1 = (const float*)d_in[9];
    const float* mw2 = (const float*)d_in[10];
    const float* mb2 = (const float*)d_in[11];
    const float* uw1 = (const float*)d_in[12];
    const float* ub1 = (const float*)d_in[13];
    const float* uw2 = (const float*)d_in[14];
    const float* ub2 = (const float*)d_in[15];
    const float* c1a = (const float*)d_in[16];
    const float* c1b = (const float*)d_in[17];
    const float* c1s = (const float*)d_in[18];
    const float* c2a = (const float*)d_in[19];
    const float* c2b = (const float*)d_in[20];
    const float* c2s = (const float*)d_in[21];
    const float* c3a = (const float*)d_in[22];
    const float* c3b = (const float*)d_in[23];
    const float* c3s = (const float*)d_in[24];
    const float* fcw = (const float*)d_in[25];
    const float* fcb = (const float*)d_in[26];
    float* out = (float*)d_out;
    const int* edge_i = edge_index;   // row 0

    float* ws = (float*)d_ws;
    float* a_node = ws;                ws += 262144;
    float* g_vox  = ws;                ws += 262144;
    float* n_node = ws;                ws += 262144;
    float* W_mu   = ws;                ws += 4096;
    float* b_mu   = ws;                ws += 64;
    _Float16* wemt_h = (_Float16*)ws;  ws += 2048;
    _Float16* wemt_l = (_Float16*)ws;  ws += 2048;
    _Float16* x0h = (_Float16*)ws;     ws += 131072;
    _Float16* x0l = (_Float16*)ws;     ws += 131072;
    _Float16* t2h = (_Float16*)ws;     ws += 262144;
    _Float16* t2l = (_Float16*)ws;     ws += 262144;
    _Float16* x2h = (_Float16*)ws;     ws += 262144;
    _Float16* x2l = (_Float16*)ws;     ws += 262144;
    _Float16* t3h = (_Float16*)ws;     ws += 524288;
    _Float16* t3l = (_Float16*)ws;     ws += 524288;
    float* u2 = ws;                    ws += 524288;
    float* u3 = ws;                    ws += 1048576;
    float* slab = ws;                  ws += 5242880;
    float* poolPart = ws;              ws += 4096;
    _Float16* wh = (_Float16*)ws;      ws += 4585472;   // 9170944 f16
    _Float16* wl = (_Float16*)ws;      ws += 4585472;
    // aliases valid after edge_kernel (node tables dead):
    _Float16* t1h = (_Float16*)a_node;
    _Float16* t1l = (_Float16*)(a_node + 131072);
    float* u1 = g_vox;
    _Float16* x1h = (_Float16*)n_node;
    _Float16* x1l = (_Float16*)(n_node + 131072);

    _Float16* w1a_h = wh + 0;       _Float16* w1a_l = wl + 0;
    _Float16* w1b_h = wh + 110592;  _Float16* w1b_l = wl + 110592;
    _Float16* w1s_h = wh + 221184;  _Float16* w1s_l = wl + 221184;
    _Float16* w2a_h = wh + 733184;  _Float16* w2a_l = wl + 733184;
    _Float16* w2b_h = wh + 954368;  _Float16* w2b_l = wl + 954368;
    _Float16* w2s_h = wh + 1396736; _Float16* w2s_l = wl + 1396736;
    _Float16* w3a_h = wh + 2420736; _Float16* w3a_l = wl + 2420736;
    _Float16* w3b_h = wh + 3305472; _Float16* w3b_l = wl + 3305472;
    _Float16* w3s_h = wh + 5074944; _Float16* w3s_l = wl + 5074944;

    // ---- weight transpose + split ----
    hipLaunchKernelGGL((wsplit_k<27,1,2>),  dim3(64,2),  dim3(256), 0, stream, c1a, w1a_h, w1a_l, 64);
    hipLaunchKernelGGL((wsplit_k<27,1,2>),  dim3(64,2),  dim3(256), 0, stream, c1b, w1b_h, w1b_l, 64);
    hipLaunchKernelGGL((wsplit_k<125,1,2>), dim3(64,2),  dim3(256), 0, stream, c1s, w1s_h, w1s_l, 64);
    hipLaunchKernelGGL((wsplit_k<27,2,2>),  dim3(128,2), dim3(256), 0, stream, c2a, w2a_h, w2a_l, 64);
    hipLaunchKernelGGL((wsplit_k<27,2,4>),  dim3(128,4), dim3(256), 0, stream, c2b, w2b_h, w2b_l, 128);
    hipLaunchKernelGGL((wsplit_k<125,2,2>), dim3(128,2), dim3(256), 0, stream, c2s, w2s_h, w2s_l, 64);
    hipLaunchKernelGGL((wsplit_k<27,4,4>),  dim3(256,4), dim3(256), 0, stream, c3a, w3a_h, w3a_l, 128);
    hipLaunchKernelGGL((wsplit_k<27,4,8>),  dim3(256,8), dim3(256), 0, stream, c3b, w3b_h, w3b_l, 256);
    hipLaunchKernelGGL((wsplit_k<125,4,4>), dim3(256,4), dim3(256), 0, stream, c3s, w3s_h, w3s_l, 128);

    // ---- MPNN ----
    hipLaunchKernelGGL(prep_w_k, dim3(64), dim3(64), 0, stream,
                       ew2, mw1, mw2, uw1, mb2, ub1, W_mu, b_mu, wemt_h, wemt_l);
    hipLaunchKernelGGL(prep_nodes_k, dim3(4096), dim3(64), 0, stream,
                       node_embedding, node_pos, grid_pos, ew1, eb1, mw1, mb1, eb2,
                       a_node, g_vox, n_node);
    hipLaunchKernelGGL(edge_kernel, dim3(4096), dim3(256), 0, stream,
                       edge_i, a_node, g_vox, n_node, wemt_h, wemt_l,
                       W_mu, b_mu, uw2, ub2, x0h, x0l);

    // ---- ResNet3D ----
    // Block 1: 64 -> 64  (ci-split 2: S = 2*KK slabs)
    hipLaunchKernelGGL((conv_mfma_k<3,64,1,2>), dim3(16,1,6), dim3(256), 0, stream, x0h, x0l, w1a_h, w1a_l, slab);
    hipLaunchKernelGGL((reduce_k<6,1,1>), dim3(16,8), dim3(256), 0, stream, slab, (const float*)nullptr, (float*)nullptr, t1h, t1l, 64);
    hipLaunchKernelGGL((conv_mfma_k<3,64,1,2>), dim3(16,1,6), dim3(256), 0, stream, t1h, t1l, w1b_h, w1b_l, slab);
    hipLaunchKernelGGL((reduce_k<6,2,0>), dim3(16,8), dim3(256), 0, stream, slab, (const float*)nullptr, u1, (_Float16*)nullptr, (_Float16*)nullptr, 64);
    hipLaunchKernelGGL((conv_mfma_k<5,64,1,2>), dim3(16,1,10), dim3(256), 0, stream, x0h, x0l, w1s_h, w1s_l, slab);
    hipLaunchKernelGGL((reduce_k<10,3,1>), dim3(16,8), dim3(256), 0, stream, slab, u1, (float*)nullptr, x1h, x1l, 64);
    // Block 2: 64 -> 128
    hipLaunchKernelGGL((conv_mfma_k<3,64,2,2>), dim3(16,2,6), dim3(256), 0, stream, x1h, x1l, w2a_h, w2a_l, slab);
    hipLaunchKernelGGL((reduce_k<6,1,1>), dim3(16,16), dim3(256), 0, stream, slab, (const float*)nullptr, (float*)nullptr, t2h, t2l, 128);
    hipLaunchKernelGGL((conv_mfma_k<3,128,2,2>), dim3(16,2,6), dim3(256), 0, stream, t2h, t2l, w2b_h, w2b_l, slab);
    hipLaunchKernelGGL((reduce_k<6,2,0>), dim3(16,16), dim3(256), 0, stream, slab, (const float*)nullptr, u2, (_Float16*)nullptr, (_Float16*)nullptr, 128);
    hipLaunchKernelGGL((conv_mfma_k<5,64,2,2>), dim3(16,2,10), dim3(256), 0, stream, x1h, x1l, w2s_h, w2s_l, slab);
    hipLaunchKernelGGL((reduce_k<10,3,1>), dim3(16,16), dim3(256), 0, stream, slab, u2, (float*)nullptr, x2h, x2l, 128);
    // Block 3: 128 -> 256  (no ci-split: slab budget)
    hipLaunchKernelGGL((conv_mfma_k<3,128,4,1>), dim3(16,4,3), dim3(256), 0, stream, x2h, x2l, w3a_h, w3a_l, slab);
    hipLaunchKernelGGL((reduce_k<3,1,1>), dim3(16,32), dim3(256), 0, stream, slab, (const float*)nullptr, (float*)nullptr, t3h, t3l, 256);
    hipLaunchKernelGGL((conv_mfma_k<3,256,4,1>), dim3(16,4,3), dim3(256), 0, stream, t3h, t3l, w3b_h, w3b_l, slab);
    hipLaunchKernelGGL((reduce_k<3,2,0>), dim3(16,32), dim3(256), 0, stream, slab, (const float*)nullptr, u3, (_Float16*)nullptr, (_Float16*)nullptr, 256);
    hipLaunchKernelGGL((conv_mfma_k<5,128,4,1>), dim3(16,4,5), dim3(256), 0, stream, x2h, x2l, w3s_h, w3s_l, slab);
    hipLaunchKernelGGL((reduce_k<5,3,2>), dim3(16,32), dim3(256), 0, stream, slab, u3, poolPart, (_Float16*)nullptr, (_Float16*)nullptr, 256);

    hipLaunchKernelGGL(fc_k, dim3(1), dim3(256), 0, stream, poolPart, fcw, fcb, out);

    (void)in_sizes; (void)n_in; (void)out_size; (void)ws_size;
}

// Round 8
// 521.031 us; speedup vs baseline: 1.4654x; 1.4654x over previous
//
#include <hip/hip_runtime.h>
#include <math.h>

// eval-mode BatchNorm3d scale: np.float32(1/sqrt(1+1e-5))
#define BN_S 0.9999950000374997f

typedef _Float16 half8 __attribute__((ext_vector_type(8)));
typedef float f32x4 __attribute__((ext_vector_type(4)));

__device__ __forceinline__ float silu_f(float x) {
    return __fdividef(x, 1.0f + __expf(-x));
}

// global -> LDS async DMA, 16B per lane (lane-linear LDS destination)
__device__ __forceinline__ void gld16(const void* g, void* l) {
    __builtin_amdgcn_global_load_lds(
        (const __attribute__((address_space(1))) void*)g,
        (__attribute__((address_space(3))) void*)l, 16, 0, 0);
}

// ---------------------------------------------------------------------------
// Prep: W_mu = mw2 @ uw1, b_mu = mb2 @ uw1 + ub1, and W_em^T = (ew2 @ mw1[64:])^T
// split to fp16 hi/lo in the edge kernel's DMA/frag layout (XOR-swizzled).
// ---------------------------------------------------------------------------
__global__ __launch_bounds__(64) void prep_w_k(
    const float* __restrict__ ew2, const float* __restrict__ mw1,
    const float* __restrict__ mw2, const float* __restrict__ uw1,
    const float* __restrict__ mb2, const float* __restrict__ ub1,
    float* __restrict__ W_mu, float* __restrict__ b_mu,
    _Float16* __restrict__ wemt_h, _Float16* __restrict__ wemt_l)
{
    const int k = blockIdx.x, c = threadIdx.x;
    float s = 0.f;
    for (int m = 0; m < 64; m++) s = fmaf(ew2[k*64 + m], mw1[(64 + m)*64 + c], s);
    {
        const int q = k >> 5, kg = (k >> 3) & 3, jj = k & 7;
        const int sl = q*256 + c*4 + kg;
        const int p = sl ^ ((sl >> 3) & 7);
        const _Float16 h = (_Float16)s;
        const _Float16 l = (_Float16)(s - (float)h);
        wemt_h[p*8 + jj] = h;
        wemt_l[p*8 + jj] = l;
    }
    float s2 = 0.f;
    for (int m = 0; m < 64; m++) s2 = fmaf(mw2[k*64 + m], uw1[m*64 + c], s2);
    W_mu[k*64 + c] = s2;
    if (k == 0) {
        float s3 = ub1[c];
        for (int m = 0; m < 64; m++) s3 = fmaf(mb2[m], uw1[m*64 + c], s3);
        b_mu[c] = s3;
    }
}

// ---------------------------------------------------------------------------
__global__ __launch_bounds__(64) void prep_nodes_k(
    const float* __restrict__ node_embedding, const float* __restrict__ node_pos,
    const float* __restrict__ grid_pos, const float* __restrict__ ew1,
    const float* __restrict__ eb1, const float* __restrict__ mw1,
    const float* __restrict__ mb1, const float* __restrict__ eb2,
    float* __restrict__ a_node, float* __restrict__ g_vox, float* __restrict__ n_node)
{
    const int v = blockIdx.x, c = threadIdx.x;
    const float p0 = node_pos[v*3], p1 = node_pos[v*3 + 1], p2 = node_pos[v*3 + 2];
    a_node[v*64 + c] = fmaf(p0, ew1[c], fmaf(p1, ew1[64 + c], fmaf(p2, ew1[128 + c], eb1[c])));
    const float q0 = grid_pos[v*3], q1 = grid_pos[v*3 + 1], q2 = grid_pos[v*3 + 2];
    g_vox[v*64 + c] = fmaf(q0, ew1[192 + c], fmaf(q1, ew1[256 + c], q2 * ew1[320 + c]));
    float s = mb1[c];
    for (int k = 0; k < 64; k++) s = fmaf(node_embedding[v*64 + k], mw1[k*64 + c], s);
    for (int k = 0; k < 64; k++) s = fmaf(eb2[k], mw1[(64 + k)*64 + c], s);
    n_node[v*64 + c] = s;
}

// ---------------------------------------------------------------------------
// Weight transpose + fp16 hi/lo split into conv layout (unchanged):
// per (tap, coG64, ch): 2048 f16 = [co64][ci32] with 16B-slot XOR swizzle.
// ---------------------------------------------------------------------------
template<int K3, int NCOG, int NCH>
__global__ __launch_bounds__(256) void wsplit_k(
    const float* __restrict__ w, _Float16* __restrict__ dh, _Float16* __restrict__ dl,
    int CI)
{
    __shared__ float s[32*K3];
    const int co = blockIdx.x, cig = blockIdx.y, t = threadIdx.x;
    const float* src = w + ((size_t)co*CI + cig*32)*K3;
    for (int m = t; m < 32*K3; m += 256) s[m] = src[m];
    __syncthreads();
    const int coG = co >> 6, col = co & 63;
    for (int m = t; m < 32*K3; m += 256) {
        const int tap = m >> 5, cil = m & 31;
        const float x = s[cil*K3 + tap];
        const _Float16 h = (_Float16)x;
        const _Float16 l = (_Float16)(x - (float)h);
        const int b = cil >> 3, jj = cil & 7;
        const int sl = col*4 + b;
        const int p = sl ^ ((sl >> 3) & 7);
        const size_t base = ((size_t)(tap*NCOG + coG)*NCH + cig) * 2048;
        dh[base + p*8 + jj] = h;
        dl[base + p*8 + jj] = l;
    }
}

// ---------------------------------------------------------------------------
// Edge kernel, MFMA version (unchanged — passed with absmax 0.0).
// ---------------------------------------------------------------------------
__global__ __launch_bounds__(256) void edge_kernel(
    const int* __restrict__ edge_i,
    const float* __restrict__ a_node, const float* __restrict__ g_vox,
    const float* __restrict__ n_node,
    const _Float16* __restrict__ wemt_h, const _Float16* __restrict__ wemt_l,
    const float* __restrict__ W_mu, const float* __restrict__ b_mu,
    const float* __restrict__ uw2, const float* __restrict__ ub2,
    _Float16* __restrict__ x0h, _Float16* __restrict__ x0l)
{
    __shared__ __align__(16) _Float16 sAh[4096], sAl[4096];
    __shared__ __align__(16) _Float16 sBh[4096], sBl[4096];
    __shared__ float sV1[64], sV2[64];

    const int j = blockIdx.x, t = threadIdx.x;
    const int lane = t & 63, wv = t >> 6, ln15 = lane & 15, kg = lane >> 4;
    const int ebase = j << 8;

    gld16(wemt_h + t*8, &sAh[t*8]);
    gld16(wemt_h + 2048 + t*8, &sAh[2048 + t*8]);
    gld16(wemt_l + t*8, &sAl[t*8]);
    gld16(wemt_l + 2048 + t*8, &sAl[2048 + t*8]);

    const int r = t >> 2, sub = t & 3;
    float gv[16];
    #pragma unroll
    for (int m = 0; m < 16; m++) gv[m] = g_vox[j*64 + sub*16 + m];

    asm volatile("s_waitcnt vmcnt(0)" ::: "memory");
    __syncthreads();

    float psum[4] = {0.f, 0.f, 0.f, 0.f};

    for (int T = 0; T < 4; T++) {
        {
            const int i = edge_i[ebase + T*64 + r];
            float s1[16];
            #pragma unroll
            for (int m = 0; m < 16; m++)
                s1[m] = silu_f(a_node[i*64 + sub*16 + m] + gv[m]);
            half8 h0, l0, h1, l1;
            #pragma unroll
            for (int m = 0; m < 8; m++) {
                h0[m] = (_Float16)s1[m];
                l0[m] = (_Float16)(s1[m] - (float)h0[m]);
                h1[m] = (_Float16)s1[8 + m];
                l1[m] = (_Float16)(s1[8 + m] - (float)h1[m]);
            }
            const int q = sub >> 1, kg0 = (sub & 1) * 2;
            const int slot0 = (q*4 + kg0)*64 + r;
            *(half8*)&sBh[slot0*8] = h0; *(half8*)&sBl[slot0*8] = l0;
            *(half8*)&sBh[(slot0 + 64)*8] = h1; *(half8*)&sBl[(slot0 + 64)*8] = l1;
        }
        __syncthreads();
        #pragma unroll
        for (int eF = 0; eF < 4; eF++) {
            const int e = eF*16 + ln15;
            const int ie = edge_i[ebase + T*64 + e];
            f32x4 acc;
            {
                const float4 nv = *(const float4*)&n_node[(size_t)ie*64 + wv*16 + kg*4];
                acc[0] = nv.x; acc[1] = nv.y; acc[2] = nv.z; acc[3] = nv.w;
            }
            #pragma unroll
            for (int q = 0; q < 2; q++) {
                const int sa = q*256 + (wv*16 + ln15)*4 + kg;
                const int pa = sa ^ ((sa >> 3) & 7);
                const half8 Ah = *(const half8*)&sAh[pa*8];
                const half8 Al = *(const half8*)&sAl[pa*8];
                const int sb = ((q*4 + kg)*64 + e)*8;
                const half8 Bh = *(const half8*)&sBh[sb];
                const half8 Bl = *(const half8*)&sBl[sb];
                acc = __builtin_amdgcn_mfma_f32_16x16x32_f16(Ah, Bh, acc, 0, 0, 0);
                acc = __builtin_amdgcn_mfma_f32_16x16x32_f16(Ah, Bl, acc, 0, 0, 0);
                acc = __builtin_amdgcn_mfma_f32_16x16x32_f16(Al, Bh, acc, 0, 0, 0);
            }
            #pragma unroll
            for (int rg = 0; rg < 4; rg++) psum[rg] += silu_f(acc[rg]);
        }
        __syncthreads();
    }

    #pragma unroll
    for (int rg = 0; rg < 4; rg++) {
        float v = psum[rg];
        v += __shfl_xor(v, 1, 64); v += __shfl_xor(v, 2, 64);
        v += __shfl_xor(v, 4, 64); v += __shfl_xor(v, 8, 64);
        psum[rg] = v;
    }
    if (ln15 == 0) {
        #pragma unroll
        for (int rg = 0; rg < 4; rg++)
            sV1[wv*16 + kg*4 + rg] = psum[rg] * (1.0f / 256.0f);
    }
    __syncthreads();
    if (t < 64) {
        float h = b_mu[t];
        for (int k = 0; k < 64; k++) h = fmaf(sV1[k], W_mu[k*64 + t], h);
        sV2[t] = silu_f(h);
    }
    __syncthreads();
    if (t < 64) {
        float g = ub2[t];
        for (int k = 0; k < 64; k++) g = fmaf(sV2[k], uw2[k*64 + t], g);
        const float val = g * BN_S;
        const _Float16 hh = (_Float16)val;
        const _Float16 ll = (_Float16)(val - (float)hh);
        const int c = t, zz = j >> 8, v = j & 255;
        const size_t a16 = ((size_t)((c >> 5)*16 + zz)*1024 + ((c >> 3) & 3)*256 + v)*8 + (c & 7);
        x0h[a16] = hh; x0l[a16] = ll;
    }
}

// ---------------------------------------------------------------------------
// Conv3D via MFMA shift-GEMM v7: R6 pipeline, but wave tile = 32co x 64vox
// (cf=2) -> 2x total waves (occupancy was wave-count-bound, not LDS-bound).
// A: register double-buffer prefetched one tap ahead; B: loaded in-burst;
// X: LDS double-buffer, DMA issued at chunk start, one drain per chunk.
// grid(d0=16, coG32 = CO/32, z = cis*KK + kd); slab index = blockIdx.z.
// ---------------------------------------------------------------------------
template<int KK, int CI, int NCO32, int CIS>
__global__ __launch_bounds__(256) void conv_mfma_k(
    const _Float16* __restrict__ xh, const _Float16* __restrict__ xl,
    const _Float16* __restrict__ wh, const _Float16* __restrict__ wl,
    float* __restrict__ slab)
{
    constexpr int P = KK/2, K2 = KK*KK, NCH = CI/32, NCHS = NCH/CIS;
    constexpr int CO = NCO32*32, NCOG64 = NCO32/2;
    const int d0 = blockIdx.x, coG32 = blockIdx.y;
    const int co64G = coG32 >> 1, coHalf = coG32 & 1;
    const int cis = blockIdx.z / KK, kd = blockIdx.z % KK;
    const int t = threadIdx.x;
    const int lane = t & 63, wv = t >> 6;
    const int ln15 = lane & 15, kg = lane >> 4;

    float* sout = slab + ((size_t)blockIdx.z*CO + coG32*32)*4096 + d0*256;
    const int z = d0 + kd - P;
    if ((unsigned)z >= 16u) {   // OOB depth plane -> zero partial
        for (int m = t; m < 32*256; m += 256)
            sout[(size_t)(m >> 8)*4096 + (m & 255)] = 0.f;
        return;
    }

    __shared__ __align__(16) _Float16 sXh[2][8192];   // 32 KB
    __shared__ __align__(16) _Float16 sXl[2][8192];   // 32 KB
    __shared__ __align__(16) _Float16 zb[8];
    if (t < 8) zb[t] = (_Float16)0.f;

    // per-lane A fragment offsets (swizzled within co64 tile), 2 cf frags
    int aoff[2];
    #pragma unroll
    for (int cf = 0; cf < 2; cf++) {
        const int s = (coHalf*32 + cf*16 + ln15)*4 + kg;
        aoff[cf] = (s ^ ((s >> 3) & 7)) * 8;
    }

    auto stage_X = [&](int xb, int ch) {
        const size_t b16 = ((size_t)ch*16 + z) * 8192;
        #pragma unroll
        for (int q = 0; q < 4; q++) {
            gld16(xh + b16 + (q*256 + t)*8, &sXh[xb][(q*256 + t)*8]);
            gld16(xl + b16 + (q*256 + t)*8, &sXl[xb][(q*256 + t)*8]);
        }
    };
    auto loadA = [&](int ch, int t2, half8* Ah, half8* Al) {
        const size_t b = ((size_t)((kd*K2 + t2)*NCOG64 + co64G)*NCH + ch) * 2048;
        #pragma unroll
        for (int cf = 0; cf < 2; cf++) {
            Ah[cf] = *(const half8*)&wh[b + aoff[cf]];
            Al[cf] = *(const half8*)&wl[b + aoff[cf]];
        }
    };

    f32x4 acc[2][4];
    #pragma unroll
    for (int a = 0; a < 2; a++)
        #pragma unroll
        for (int b = 0; b < 4; b++)
            #pragma unroll
            for (int r2 = 0; r2 < 4; r2++) acc[a][b][r2] = 0.f;

    const int ch0 = cis * NCHS;
    half8 nAh[2], nAl[2];
    stage_X(0, ch0);
    loadA(ch0, 0, nAh, nAl);
    asm volatile("s_waitcnt vmcnt(0)" ::: "memory");
    __syncthreads();

    for (int cc = 0; cc < NCHS; cc++) {
        const int ch = ch0 + cc, xb = cc & 1;
        if (cc + 1 < NCHS) stage_X(xb ^ 1, ch + 1);   // DMA flies across the chunk
        for (int t2 = 0; t2 < K2; t2++) {
            half8 cAh[2], cAl[2];
            #pragma unroll
            for (int cf = 0; cf < 2; cf++) { cAh[cf] = nAh[cf]; cAl[cf] = nAl[cf]; }
            if (t2 + 1 < K2)          loadA(ch, t2 + 1, nAh, nAl);
            else if (cc + 1 < NCHS)   loadA(ch + 1, 0, nAh, nAl);

            const int kh = t2 / KK, kw = t2 % KK;
            __builtin_amdgcn_s_setprio(1);
            #pragma unroll
            for (int f = 0; f < 4; f++) {
                const int h_in = wv*4 + f + kh - P;
                if ((unsigned)h_in < 16u) {
                    const int w_in = ln15 + kw - P;
                    const bool ok = (unsigned)w_in < 16u;
                    const int slot = ok ? (kg*256 + h_in*16 + w_in) : 0;
                    const half8 Bh = ok ? *(const half8*)&sXh[xb][slot*8] : *(const half8*)zb;
                    const half8 Bl = ok ? *(const half8*)&sXl[xb][slot*8] : *(const half8*)zb;
                    #pragma unroll
                    for (int cf = 0; cf < 2; cf++) {
                        acc[cf][f] = __builtin_amdgcn_mfma_f32_16x16x32_f16(cAh[cf], Bh, acc[cf][f], 0, 0, 0);
                        acc[cf][f] = __builtin_amdgcn_mfma_f32_16x16x32_f16(cAh[cf], Bl, acc[cf][f], 0, 0, 0);
                        acc[cf][f] = __builtin_amdgcn_mfma_f32_16x16x32_f16(cAl[cf], Bh, acc[cf][f], 0, 0, 0);
                    }
                }
            }
            __builtin_amdgcn_s_setprio(0);
        }
        asm volatile("s_waitcnt vmcnt(0)" ::: "memory");
        __syncthreads();   // next-chunk staging landed; buffer xb free next iter
    }

    // C frag: col=lane&15 (vox), row=(lane>>4)*4+reg (co within 32)
    #pragma unroll
    for (int cf = 0; cf < 2; cf++)
        #pragma unroll
        for (int f = 0; f < 4; f++)
            #pragma unroll
            for (int r2 = 0; r2 < 4; r2++)
                sout[(size_t)(cf*16 + kg*4 + r2)*4096 + wv*64 + f*16 + ln15] = acc[cf][f][r2];
}

// ---------------------------------------------------------------------------
// Reduce S kd/cis-slabs + BN (+residual) (+relu); emit fp32 / fp16-split /
// poolmax partials. grid(16 z, CO/8).
// ---------------------------------------------------------------------------
template<int S, int RMODE, int OUT>
__global__ __launch_bounds__(256) void reduce_k(
    const float* __restrict__ pbuf, const float* __restrict__ addsrc,
    float* __restrict__ outf, _Float16* __restrict__ oh, _Float16* __restrict__ ol,
    int CO)
{
    const int z = blockIdx.x, c8 = blockIdx.y, v = threadIdx.x;
    float val[8];
    #pragma unroll
    for (int jj = 0; jj < 8; jj++) {
        const int c = c8*8 + jj;
        float a = 0.f;
        #pragma unroll
        for (int s = 0; s < S; s++)
            a += pbuf[((size_t)s*CO + c)*4096 + z*256 + v];
        a *= BN_S;
        if (RMODE == 3) a += addsrc[(size_t)c*4096 + z*256 + v];
        if (RMODE != 2) a = fmaxf(a, 0.f);
        val[jj] = a;
    }
    if (OUT == 0) {
        #pragma unroll
        for (int jj = 0; jj < 8; jj++)
            outf[(size_t)(c8*8 + jj)*4096 + z*256 + v] = val[jj];
    } else if (OUT == 1) {
        half8 hv, lv;
        #pragma unroll
        for (int jj = 0; jj < 8; jj++) {
            hv[jj] = (_Float16)val[jj];
            lv[jj] = (_Float16)(val[jj] - (float)hv[jj]);
        }
        const size_t a16 = ((size_t)((c8 >> 2)*16 + z)*1024 + (c8 & 3)*256 + v)*8;
        *(half8*)&oh[a16] = hv;
        *(half8*)&ol[a16] = lv;
    } else {
        __shared__ float sm[4][8];
        #pragma unroll
        for (int jj = 0; jj < 8; jj++) {
            float m = val[jj];
            m = fmaxf(m, __shfl_xor(m, 1, 64));  m = fmaxf(m, __shfl_xor(m, 2, 64));
            m = fmaxf(m, __shfl_xor(m, 4, 64));  m = fmaxf(m, __shfl_xor(m, 8, 64));
            m = fmaxf(m, __shfl_xor(m, 16, 64)); m = fmaxf(m, __shfl_xor(m, 32, 64));
            if ((v & 63) == 0) sm[v >> 6][jj] = m;
        }
        __syncthreads();
        if (v < 8) {
            const float m = fmaxf(fmaxf(sm[0][v], sm[1][v]), fmaxf(sm[2][v], sm[3][v]));
            outf[z*CO + c8*8 + v] = m;
        }
    }
}

// ---------------------------------------------------------------------------
__global__ __launch_bounds__(256) void fc_k(
    const float* __restrict__ pp, const float* __restrict__ fcw,
    const float* __restrict__ fcb, float* __restrict__ out)
{
    __shared__ float sp[256];
    const int t = threadIdx.x;
    float m = pp[t];
    for (int zz = 1; zz < 16; zz++) m = fmaxf(m, pp[zz*256 + t]);
    sp[t] = m;
    __syncthreads();
    if (t < 20) {
        float s = fcb[t];
        for (int c = 0; c < 256; c++) s = fmaf(sp[c], fcw[c*20 + t], s);
        out[t] = s;
    }
}

// ---------------------------------------------------------------------------
extern "C" void kernel_launch(void* const* d_in, const int* in_sizes, int n_in,
                              void* d_out, int out_size, void* d_ws, size_t ws_size,
                              hipStream_t stream)
{
    const float* node_embedding = (const float*)d_in[0];
    const float* node_pos       = (const float*)d_in[1];
    const float* grid_pos       = (const float*)d_in[2];
    const int*   edge_index     = (const int*)d_in[3];
    const float* ew1 = (const float*)d_in[4];
    const float* eb1 = (const float*)d_in[5];
    const float* ew2 = (const float*)d_in[6];
    const float* eb2 = (const float*)d_in[7];
    const float* mw1 = (const float*)d_in[8];
    const float* mb1 = (const float*)d_in[9];
    const float* mw2 = (const float*)d_in[10];
    const float* mb2 = (const float*)d_in[11];
    const float* uw1 = (const float*)d_in[12];
    const float* ub1 = (const float*)d_in[13];
    const float* uw2 = (const float*)d_in[14];
    const float* ub2 = (const float*)d_in[15];
    const float* c1a = (const float*)d_in[16];
    const float* c1b = (const float*)d_in[17];
    const float* c1s = (const float*)d_in[18];
    const float* c2a = (const float*)d_in[19];
    const float* c2b = (const float*)d_in[20];
    const float* c2s = (const float*)d_in[21];
    const float* c3a = (const float*)d_in[22];
    const float* c3b = (const float*)d_in[23];
    const float* c3s = (const float*)d_in[24];
    const float* fcw = (const float*)d_in[25];
    const float* fcb = (const float*)d_in[26];
    float* out = (float*)d_out;
    const int* edge_i = edge_index;   // row 0

    float* ws = (float*)d_ws;
    float* a_node = ws;                ws += 262144;
    float* g_vox  = ws;                ws += 262144;
    float* n_node = ws;                ws += 262144;
    float* W_mu   = ws;                ws += 4096;
    float* b_mu   = ws;                ws += 64;
    _Float16* wemt_h = (_Float16*)ws;  ws += 2048;
    _Float16* wemt_l = (_Float16*)ws;  ws += 2048;
    _Float16* x0h = (_Float16*)ws;     ws += 131072;
    _Float16* x0l = (_Float16*)ws;     ws += 131072;
    _Float16* t2h = (_Float16*)ws;     ws += 262144;
    _Float16* t2l = (_Float16*)ws;     ws += 262144;
    _Float16* x2h = (_Float16*)ws;     ws += 262144;
    _Float16* x2l = (_Float16*)ws;     ws += 262144;
    _Float16* t3h = (_Float16*)ws;     ws += 524288;
    _Float16* t3l = (_Float16*)ws;     ws += 524288;
    float* u2 = ws;                    ws += 524288;
    float* u3 = ws;                    ws += 1048576;
    float* slab = ws;                  ws += 5242880;
    float* poolPart = ws;              ws += 4096;
    _Float16* wh = (_Float16*)ws;      ws += 4585472;   // 9170944 f16
    _Float16* wl = (_Float16*)ws;      ws += 4585472;
    // aliases valid after edge_kernel (node tables dead):
    _Float16* t1h = (_Float16*)a_node;
    _Float16* t1l = (_Float16*)(a_node + 131072);
    float* u1 = g_vox;
    _Float16* x1h = (_Float16*)n_node;
    _Float16* x1l = (_Float16*)(n_node + 131072);

    _Float16* w1a_h = wh + 0;       _Float16* w1a_l = wl + 0;
    _Float16* w1b_h = wh + 110592;  _Float16* w1b_l = wl + 110592;
    _Float16* w1s_h = wh + 221184;  _Float16* w1s_l = wl + 221184;
    _Float16* w2a_h = wh + 733184;  _Float16* w2a_l = wl + 733184;
    _Float16* w2b_h = wh + 954368;  _Float16* w2b_l = wl + 954368;
    _Float16* w2s_h = wh + 1396736; _Float16* w2s_l = wl + 1396736;
    _Float16* w3a_h = wh + 2420736; _Float16* w3a_l = wl + 2420736;
    _Float16* w3b_h = wh + 3305472; _Float16* w3b_l = wl + 3305472;
    _Float16* w3s_h = wh + 5074944; _Float16* w3s_l = wl + 5074944;

    // ---- weight transpose + split ----
    hipLaunchKernelGGL((wsplit_k<27,1,2>),  dim3(64,2),  dim3(256), 0, stream, c1a, w1a_h, w1a_l, 64);
    hipLaunchKernelGGL((wsplit_k<27,1,2>),  dim3(64,2),  dim3(256), 0, stream, c1b, w1b_h, w1b_l, 64);
    hipLaunchKernelGGL((wsplit_k<125,1,2>), dim3(64,2),  dim3(256), 0, stream, c1s, w1s_h, w1s_l, 64);
    hipLaunchKernelGGL((wsplit_k<27,2,2>),  dim3(128,2), dim3(256), 0, stream, c2a, w2a_h, w2a_l, 64);
    hipLaunchKernelGGL((wsplit_k<27,2,4>),  dim3(128,4), dim3(256), 0, stream, c2b, w2b_h, w2b_l, 128);
    hipLaunchKernelGGL((wsplit_k<125,2,2>), dim3(128,2), dim3(256), 0, stream, c2s, w2s_h, w2s_l, 64);
    hipLaunchKernelGGL((wsplit_k<27,4,4>),  dim3(256,4), dim3(256), 0, stream, c3a, w3a_h, w3a_l, 128);
    hipLaunchKernelGGL((wsplit_k<27,4,8>),  dim3(256,8), dim3(256), 0, stream, c3b, w3b_h, w3b_l, 256);
    hipLaunchKernelGGL((wsplit_k<125,4,4>), dim3(256,4), dim3(256), 0, stream, c3s, w3s_h, w3s_l, 128);

    // ---- MPNN ----
    hipLaunchKernelGGL(prep_w_k, dim3(64), dim3(64), 0, stream,
                       ew2, mw1, mw2, uw1, mb2, ub1, W_mu, b_mu, wemt_h, wemt_l);
    hipLaunchKernelGGL(prep_nodes_k, dim3(4096), dim3(64), 0, stream,
                       node_embedding, node_pos, grid_pos, ew1, eb1, mw1, mb1, eb2,
                       a_node, g_vox, n_node);
    hipLaunchKernelGGL(edge_kernel, dim3(4096), dim3(256), 0, stream,
                       edge_i, a_node, g_vox, n_node, wemt_h, wemt_l,
                       W_mu, b_mu, uw2, ub2, x0h, x0l);

    // ---- ResNet3D ----
    // Block 1: 64 -> 64  (ci-split 2: S = 2*KK slabs)
    hipLaunchKernelGGL((conv_mfma_k<3,64,2,2>), dim3(16,2,6), dim3(256), 0, stream, x0h, x0l, w1a_h, w1a_l, slab);
    hipLaunchKernelGGL((reduce_k<6,1,1>), dim3(16,8), dim3(256), 0, stream, slab, (const float*)nullptr, (float*)nullptr, t1h, t1l, 64);
    hipLaunchKernelGGL((conv_mfma_k<3,64,2,2>), dim3(16,2,6), dim3(256), 0, stream, t1h, t1l, w1b_h, w1b_l, slab);
    hipLaunchKernelGGL((reduce_k<6,2,0>), dim3(16,8), dim3(256), 0, stream, slab, (const float*)nullptr, u1, (_Float16*)nullptr, (_Float16*)nullptr, 64);
    hipLaunchKernelGGL((conv_mfma_k<5,64,2,2>), dim3(16,2,10), dim3(256), 0, stream, x0h, x0l, w1s_h, w1s_l, slab);
    hipLaunchKernelGGL((reduce_k<10,3,1>), dim3(16,8), dim3(256), 0, stream, slab, u1, (float*)nullptr, x1h, x1l, 64);
    // Block 2: 64 -> 128
    hipLaunchKernelGGL((conv_mfma_k<3,64,4,2>), dim3(16,4,6), dim3(256), 0, stream, x1h, x1l, w2a_h, w2a_l, slab);
    hipLaunchKernelGGL((reduce_k<6,1,1>), dim3(16,16), dim3(256), 0, stream, slab, (const float*)nullptr, (float*)nullptr, t2h, t2l, 128);
    hipLaunchKernelGGL((conv_mfma_k<3,128,4,2>), dim3(16,4,6), dim3(256), 0, stream, t2h, t2l, w2b_h, w2b_l, slab);
    hipLaunchKernelGGL((reduce_k<6,2,0>), dim3(16,16), dim3(256), 0, stream, slab, (const float*)nullptr, u2, (_Float16*)nullptr, (_Float16*)nullptr, 128);
    hipLaunchKernelGGL((conv_mfma_k<5,64,4,2>), dim3(16,4,10), dim3(256), 0, stream, x1h, x1l, w2s_h, w2s_l, slab);
    hipLaunchKernelGGL((reduce_k<10,3,1>), dim3(16,16), dim3(256), 0, stream, slab, u2, (float*)nullptr, x2h, x2l, 128);
    // Block 3: 128 -> 256  (no ci-split: slab budget)
    hipLaunchKernelGGL((conv_mfma_k<3,128,8,1>), dim3(16,8,3), dim3(256), 0, stream, x2h, x2l, w3a_h, w3a_l, slab);
    hipLaunchKernelGGL((reduce_k<3,1,1>), dim3(16,32), dim3(256), 0, stream, slab, (const float*)nullptr, (float*)nullptr, t3h, t3l, 256);
    hipLaunchKernelGGL((conv_mfma_k<3,256,8,1>), dim3(16,8,3), dim3(256), 0, stream, t3h, t3l, w3b_h, w3b_l, slab);
    hipLaunchKernelGGL((reduce_k<3,2,0>), dim3(16,32), dim3(256), 0, stream, slab, (const float*)nullptr, u3, (_Float16*)nullptr, (_Float16*)nullptr, 256);
    hipLaunchKernelGGL((conv_mfma_k<5,128,8,1>), dim3(16,8,5), dim3(256), 0, stream, x2h, x2l, w3s_h, w3s_l, slab);
    hipLaunchKernelGGL((reduce_k<5,3,2>), dim3(16,32), dim3(256), 0, stream, slab, u3, poolPart, (_Float16*)nullptr, (_Float16*)nullptr, 256);

    hipLaunchKernelGGL(fc_k, dim3(1), dim3(256), 0, stream, poolPart, fcw, fcb, out);

    (void)in_sizes; (void)n_in; (void)out_size; (void)ws_size;
}